// Round 1
// baseline (138.612 us; speedup 1.0000x reference)
//
#include <hip/hip_runtime.h>

// Sliding-window causal attention, B=2 H=8 S=4096 D=64, window=512.
// Flash-style: 1 block = 64 queries for one (b,h); 4 waves x 16 queries.
// bf16 MFMA (16x16x32), fp32 accumulate, online softmax per wave.

#define NBATCH 2
#define NHEAD  8
#define SEQ    4096
#define DH     64
#define WIN    512
#define QT     64     // queries per block
#define LDP    72     // padded LDS row (ushorts): stride 72*2=144 B -> conflict-free b128 frag reads

typedef __attribute__((ext_vector_type(4))) float f32x4;
typedef __attribute__((ext_vector_type(8))) short bf16x8;   // 8 bf16 in 4 VGPRs (guide-verified operand type)

__device__ __forceinline__ unsigned short f2bf(float f) {
  // round-to-nearest-even fp32 -> bf16
  unsigned u = __builtin_bit_cast(unsigned, f);
  u += 0x7fffu + ((u >> 16) & 1u);
  return (unsigned short)(u >> 16);
}

__global__ __launch_bounds__(256) void swa_attn_kernel(
    const float* __restrict__ Qg, const float* __restrict__ Kg,
    const float* __restrict__ Vg, float* __restrict__ Og)
{
  const int qt = blockIdx.x;              // 0..63 query tile
  const int bh = blockIdx.y;              // 0..15 (b*H+h)
  const int q0 = qt * QT;
  const size_t base = (size_t)bh * SEQ * DH;

  const int t    = threadIdx.x;
  const int w    = t >> 6;                // wave 0..3 -> queries 16w..16w+15
  const int l    = t & 63;
  const int quad = l >> 4;                // 0..3
  const int lc   = l & 15;                // 0..15

  __shared__ unsigned short Qs[QT][LDP];  // [query][d]   bf16, pre-scaled by 1/8
  __shared__ unsigned short Ks[QT][LDP];  // [key][d]     bf16
  __shared__ unsigned short Vt[DH][LDP];  // [d][key]     bf16 (transposed for PV B-frags)
  __shared__ unsigned short Ps[4][16][LDP]; // per-wave P buffer: [wave][query0..15][key0..63]

  // ---------------- stage Q (scaled) ----------------
  {
    const float* src = Qg + base + (size_t)q0 * DH;
    #pragma unroll
    for (int i = 0; i < 4; ++i) {
      int e   = t + 256 * i;              // float4 chunk id, 0..1023
      int row = e >> 4;                   // 64 rows
      int d4  = (e & 15) * 4;
      float4 v = *(const float4*)(src + row * DH + d4);
      ushort4 o;
      o.x = f2bf(v.x * 0.125f); o.y = f2bf(v.y * 0.125f);
      o.z = f2bf(v.z * 0.125f); o.w = f2bf(v.w * 0.125f);
      *(ushort4*)&Qs[row][d4] = o;
    }
  }
  __syncthreads();

  // Q A-fragments: constant across all K-tiles. A[m=lc][k=32*dd + 8*quad + j]
  bf16x8 aq0 = *(const bf16x8*)&Qs[16 * w + lc][ 0 + 8 * quad];
  bf16x8 aq1 = *(const bf16x8*)&Qs[16 * w + lc][32 + 8 * quad];

  float m_r[4], l_r[4];
  f32x4 acc_o[4];                          // [d-group gn]; reg r = query quad*4+r
  #pragma unroll
  for (int r = 0; r < 4; ++r) { m_r[r] = -1e30f; l_r[r] = 0.0f; }
  #pragma unroll
  for (int g = 0; g < 4; ++g) { acc_o[g][0]=0.f; acc_o[g][1]=0.f; acc_o[g][2]=0.f; acc_o[g][3]=0.f; }

  const int kt_lo = (qt - 8 > 0) ? (qt - 8) : 0;

  // Descending: first tile processed is the causal diagonal tile, where every
  // query row has >=1 valid key -> running max becomes finite before the
  // (possibly fully-masked) leading-edge rows are seen.
  for (int kt = qt; kt >= kt_lo; --kt) {
    const int k0 = kt * QT;
    __syncthreads();  // protect Ks/Vt from previous iteration's readers
    {
      const float* srcK = Kg + base + (size_t)k0 * DH;
      const float* srcV = Vg + base + (size_t)k0 * DH;
      #pragma unroll
      for (int i = 0; i < 4; ++i) {
        int e   = t + 256 * i;
        int row = e >> 4;
        int d4  = (e & 15) * 4;
        float4 kv = *(const float4*)(srcK + row * DH + d4);
        ushort4 ko;
        ko.x = f2bf(kv.x); ko.y = f2bf(kv.y); ko.z = f2bf(kv.z); ko.w = f2bf(kv.w);
        *(ushort4*)&Ks[row][d4] = ko;
        float4 vv = *(const float4*)(srcV + row * DH + d4);
        Vt[d4 + 0][row] = f2bf(vv.x);
        Vt[d4 + 1][row] = f2bf(vv.y);
        Vt[d4 + 2][row] = f2bf(vv.z);
        Vt[d4 + 3][row] = f2bf(vv.w);
      }
    }
    __syncthreads();

    // ---------------- S = Q K^T (this wave's 16 queries x 64 keys) ----------------
    f32x4 accs[4];
    #pragma unroll
    for (int g = 0; g < 4; ++g) {
      bf16x8 b0 = *(const bf16x8*)&Ks[16 * g + lc][ 0 + 8 * quad];
      bf16x8 b1 = *(const bf16x8*)&Ks[16 * g + lc][32 + 8 * quad];
      f32x4 c; c[0]=0.f; c[1]=0.f; c[2]=0.f; c[3]=0.f;
      c = __builtin_amdgcn_mfma_f32_16x16x32_bf16(aq0, b0, c, 0, 0, 0);
      c = __builtin_amdgcn_mfma_f32_16x16x32_bf16(aq1, b1, c, 0, 0, 0);
      accs[g] = c;
    }

    // ---------------- mask + online softmax ----------------
    // C layout: score[query = 16w + 4*quad + r][key = 16g + lc] in accs[g][r]
    // allowed iff 0 >= (j-i) >= -(WIN-1)
    const int dbase = (k0 + lc) - (q0 + 16 * w + 4 * quad);  // j-i at g=0,r=0
    float p[4][4];
    float tm[4];
    #pragma unroll
    for (int r = 0; r < 4; ++r) tm[r] = -1e30f;
    #pragma unroll
    for (int g = 0; g < 4; ++g)
      #pragma unroll
      for (int r = 0; r < 4; ++r) {
        int dji = dbase + 16 * g - r;
        float s = accs[g][r];
        s = (dji <= 0 && dji >= -(WIN - 1)) ? s : -1e30f;
        p[g][r] = s;
        tm[r] = fmaxf(tm[r], s);
      }
    #pragma unroll
    for (int off = 1; off < 16; off <<= 1)
      #pragma unroll
      for (int r = 0; r < 4; ++r)
        tm[r] = fmaxf(tm[r], __shfl_xor(tm[r], off, 64));

    float alpha[4], tsum[4];
    #pragma unroll
    for (int r = 0; r < 4; ++r) {
      float mn = fmaxf(m_r[r], tm[r]);
      alpha[r] = __expf(m_r[r] - mn);
      m_r[r] = mn;
      tsum[r] = 0.0f;
    }
    #pragma unroll
    for (int g = 0; g < 4; ++g)
      #pragma unroll
      for (int r = 0; r < 4; ++r) {
        float e = __expf(p[g][r] - m_r[r]);   // masked: exp(-1e30 - finite) -> 0
        p[g][r] = e;
        tsum[r] += e;
      }
    #pragma unroll
    for (int off = 1; off < 16; off <<= 1)
      #pragma unroll
      for (int r = 0; r < 4; ++r)
        tsum[r] += __shfl_xor(tsum[r], off, 64);
    #pragma unroll
    for (int r = 0; r < 4; ++r) l_r[r] = l_r[r] * alpha[r] + tsum[r];
    #pragma unroll
    for (int g = 0; g < 4; ++g)
      #pragma unroll
      for (int r = 0; r < 4; ++r) acc_o[g][r] *= alpha[r];

    // ---------------- P: C-layout regs -> A-layout via per-wave LDS ----------------
    #pragma unroll
    for (int g = 0; g < 4; ++g)
      #pragma unroll
      for (int r = 0; r < 4; ++r)
        Ps[w][4 * quad + r][16 * g + lc] = f2bf(p[g][r]);
    __asm__ __volatile__("s_waitcnt lgkmcnt(0)" ::: "memory");  // wave-private RAW

    bf16x8 pa0 = *(const bf16x8*)&Ps[w][lc][ 0 + 8 * quad];
    bf16x8 pa1 = *(const bf16x8*)&Ps[w][lc][32 + 8 * quad];

    // ---------------- O += P V ----------------
    #pragma unroll
    for (int gn = 0; gn < 4; ++gn) {
      bf16x8 vb0 = *(const bf16x8*)&Vt[16 * gn + lc][ 0 + 8 * quad];
      bf16x8 vb1 = *(const bf16x8*)&Vt[16 * gn + lc][32 + 8 * quad];
      f32x4 c = acc_o[gn];
      c = __builtin_amdgcn_mfma_f32_16x16x32_bf16(pa0, vb0, c, 0, 0, 0);
      c = __builtin_amdgcn_mfma_f32_16x16x32_bf16(pa1, vb1, c, 0, 0, 0);
      acc_o[gn] = c;
    }
  }

  // ---------------- epilogue: O / l ----------------
  #pragma unroll
  for (int gn = 0; gn < 4; ++gn)
    #pragma unroll
    for (int r = 0; r < 4; ++r) {
      int row = q0 + 16 * w + 4 * quad + r;
      Og[base + (size_t)row * DH + 16 * gn + lc] = acc_o[gn][r] / l_r[r];
    }
}

extern "C" void kernel_launch(void* const* d_in, const int* in_sizes, int n_in,
                              void* d_out, int out_size, void* d_ws, size_t ws_size,
                              hipStream_t stream) {
  const float* Q = (const float*)d_in[0];
  const float* K = (const float*)d_in[1];
  const float* V = (const float*)d_in[2];
  float* O = (float*)d_out;
  dim3 grid(SEQ / QT, NBATCH * NHEAD);
  swa_attn_kernel<<<grid, dim3(256), 0, stream>>>(Q, K, V, O);
}

// Round 2
// 125.163 us; speedup vs baseline: 1.1075x; 1.1075x over previous
//
#include <hip/hip_runtime.h>

// Sliding-window causal attention, B=2 H=8 S=4096 D=64, window=512.
// R2: prep kernel -> bf16 K tiles + bf16 V^T tiles in XOR-swizzled 64x64 layout;
// attn kernel stages via global_load_lds (16B) with double-buffered pipeline
// (raw s_waitcnt vmcnt(0)+s_barrier, prefetch issued after barrier).

#define NBATCH 2
#define NHEAD  8
#define SEQ    4096
#define DH     64
#define WIN    512
#define QT     64

typedef __attribute__((ext_vector_type(4))) float f32x4;
typedef __attribute__((ext_vector_type(8))) short bf16x8;

typedef unsigned short ushort_t;

__device__ __forceinline__ unsigned short f2bf(float f) {
  unsigned u = __builtin_bit_cast(unsigned, f);
  u += 0x7fffu + ((u >> 16) & 1u);
  return (unsigned short)(u >> 16);
}

#define GLD16(gp, lp)                                                          \
  __builtin_amdgcn_global_load_lds(                                            \
      (const __attribute__((address_space(1))) unsigned int*)(gp),             \
      (__attribute__((address_space(3))) unsigned int*)(lp), 16, 0, 0)

// ---------------------------------------------------------------------------
// Prep: K [s][d] fp32 -> bf16 swizzled tiles; V [s][d] fp32 -> V^T [d][s] bf16
// swizzled tiles. Tile (64 rows x 8 blocks of 16B): byte offset of (row,blk) =
// row*128 + ((blk ^ (row&7))<<4). One block per (tile, bh).
// ---------------------------------------------------------------------------
__global__ __launch_bounds__(256) void prep_kernel(
    const float* __restrict__ Kg, const float* __restrict__ Vg,
    ushort_t* __restrict__ Kw, ushort_t* __restrict__ Vw)
{
  const int kt = blockIdx.x, bh = blockIdx.y;
  const size_t gbase = (size_t)bh * SEQ * DH + (size_t)kt * QT * DH;
  const size_t tbyte = ((size_t)bh * 64 + kt) * 8192;   // tile byte offset
  const int t = threadIdx.x;

  __shared__ float Vs[64][68];   // fp32 stage for V transpose (float4-aligned rows)

  // K: 512 units (row,blk), 2 per thread
  #pragma unroll
  for (int c = 0; c < 2; ++c) {
    int u = t + 256 * c;
    int row = u >> 3, blk = u & 7;
    const float* src = Kg + gbase + row * DH + blk * 8;
    float4 a = *(const float4*)src;
    float4 b = *(const float4*)(src + 4);
    union { unsigned short us[8]; uint4 q; } o;
    o.us[0]=f2bf(a.x); o.us[1]=f2bf(a.y); o.us[2]=f2bf(a.z); o.us[3]=f2bf(a.w);
    o.us[4]=f2bf(b.x); o.us[5]=f2bf(b.y); o.us[6]=f2bf(b.z); o.us[7]=f2bf(b.w);
    *(uint4*)((char*)Kw + tbyte + row * 128 + ((blk ^ (row & 7)) << 4)) = o.q;
  }

  // V: coalesced stage to LDS
  #pragma unroll
  for (int i = 0; i < 4; ++i) {
    int e = t + 256 * i;
    int row = e >> 4, c4 = (e & 15) * 4;
    *(float4*)&Vs[row][c4] = *(const float4*)(Vg + gbase + row * DH + c4);
  }
  __syncthreads();

  // V^T: out row = d, blocks of 8 keys
  #pragma unroll
  for (int c = 0; c < 2; ++c) {
    int u = t + 256 * c;
    int d = u >> 3, blk = u & 7;
    union { unsigned short us[8]; uint4 q; } o;
    #pragma unroll
    for (int j = 0; j < 8; ++j) o.us[j] = f2bf(Vs[blk * 8 + j][d]);
    *(uint4*)((char*)Vw + tbyte + d * 128 + ((blk ^ (d & 7)) << 4)) = o.q;
  }
}

// ---------------------------------------------------------------------------
// Attention kernel
// ---------------------------------------------------------------------------
__global__ __launch_bounds__(256) void swa_attn_kernel(
    const float* __restrict__ Qg, const ushort_t* __restrict__ Kw,
    const ushort_t* __restrict__ Vw, float* __restrict__ Og)
{
  const int qt = blockIdx.x;
  const int bh = blockIdx.y;
  const int q0 = qt * QT;
  const size_t base = (size_t)bh * SEQ * DH;

  const int t    = threadIdx.x;
  const int w    = t >> 6;
  const int l    = t & 63;
  const int quad = l >> 4;
  const int lc   = l & 15;
  const int lc7  = lc & 7;

  __shared__ ushort_t Ks[2][4096];   // 8 KB each, swizzled tile image
  __shared__ ushort_t Vt[2][4096];
  __shared__ ushort_t Ps[4][1024];   // per-wave P: 16 rows x 128B, swizzled
  // total LDS = 16384 + 16384 + 8192 = 40960 B -> 4 blocks/CU

  // ---- Q fragments directly from global (once) ----
  bf16x8 aq0, aq1;
  {
    const float* qrow = Qg + base + (size_t)(q0 + 16 * w + lc) * DH;
    float4 a0 = *(const float4*)(qrow + 8 * quad);
    float4 a1 = *(const float4*)(qrow + 8 * quad + 4);
    float4 b0 = *(const float4*)(qrow + 32 + 8 * quad);
    float4 b1 = *(const float4*)(qrow + 32 + 8 * quad + 4);
    union { unsigned short us[8]; bf16x8 v; } ua, ub;
    ua.us[0]=f2bf(a0.x*0.125f); ua.us[1]=f2bf(a0.y*0.125f);
    ua.us[2]=f2bf(a0.z*0.125f); ua.us[3]=f2bf(a0.w*0.125f);
    ua.us[4]=f2bf(a1.x*0.125f); ua.us[5]=f2bf(a1.y*0.125f);
    ua.us[6]=f2bf(a1.z*0.125f); ua.us[7]=f2bf(a1.w*0.125f);
    ub.us[0]=f2bf(b0.x*0.125f); ub.us[1]=f2bf(b0.y*0.125f);
    ub.us[2]=f2bf(b0.z*0.125f); ub.us[3]=f2bf(b0.w*0.125f);
    ub.us[4]=f2bf(b1.x*0.125f); ub.us[5]=f2bf(b1.y*0.125f);
    ub.us[6]=f2bf(b1.z*0.125f); ub.us[7]=f2bf(b1.w*0.125f);
    aq0 = ua.v; aq1 = ub.v;
  }

  // Conflict-free swizzled fragment base offsets (bytes, within a tile)
  const int kbase0 = lc * 128 + (((quad    ) ^ lc7) << 4);
  const int kbase1 = lc * 128 + (((quad + 4) ^ lc7) << 4);

  float m_r[4], l_r[4];
  f32x4 acc_o[4];
  #pragma unroll
  for (int r = 0; r < 4; ++r) { m_r[r] = -1e30f; l_r[r] = 0.0f; }
  #pragma unroll
  for (int g = 0; g < 4; ++g) { acc_o[g][0]=0.f; acc_o[g][1]=0.f; acc_o[g][2]=0.f; acc_o[g][3]=0.f; }

  const int kt_lo = (qt - 8 > 0) ? (qt - 8) : 0;
  const int NT = qt - kt_lo + 1;

  const size_t tile0 = ((size_t)bh * 64) * 8192;   // byte offset of tile kt=0

  // issue tile loads: 4 global_load_lds per wave (2 K + 2 V)
  auto issue = [&](int b, int kt) {
    const char* kg = (const char*)Kw + tile0 + (size_t)kt * 8192;
    const char* vg = (const char*)Vw + tile0 + (size_t)kt * 8192;
    #pragma unroll
    for (int c = 0; c < 2; ++c) {
      int off = (w * 2 + c) * 1024;
      GLD16(kg + off + l * 16, (char*)&Ks[b][0] + off);
      GLD16(vg + off + l * 16, (char*)&Vt[b][0] + off);
    }
  };

  issue(0, qt);
  int buf = 0;

  for (int i = 0; i < NT; ++i) {
    const int kt = qt - i;
    const int k0 = kt * QT;

    // wait own tile-i loads; all waves sync. Prefetch issued AFTER the
    // barrier so it can't clobber the buffer other waves still read (the
    // barrier also proves everyone finished compute on tile i-1).
    __asm__ __volatile__("s_waitcnt vmcnt(0)\n\ts_barrier" ::: "memory");
    if (i + 1 < NT) issue(buf ^ 1, kt - 1);

    // ---- S = Q K^T ----
    f32x4 accs[4];
    #pragma unroll
    for (int g = 0; g < 4; ++g) {
      bf16x8 b0 = *(const bf16x8*)((const char*)&Ks[buf][0] + kbase0 + g * 2048);
      bf16x8 b1 = *(const bf16x8*)((const char*)&Ks[buf][0] + kbase1 + g * 2048);
      f32x4 c; c[0]=0.f; c[1]=0.f; c[2]=0.f; c[3]=0.f;
      c = __builtin_amdgcn_mfma_f32_16x16x32_bf16(aq0, b0, c, 0, 0, 0);
      c = __builtin_amdgcn_mfma_f32_16x16x32_bf16(aq1, b1, c, 0, 0, 0);
      accs[g] = c;
    }

    // ---- mask (only diagonal + window-edge tiles) + online softmax ----
    float p[4][4];
    float tm[4];
    #pragma unroll
    for (int r = 0; r < 4; ++r) tm[r] = -1e30f;

    const bool need_mask = (kt == qt) || (kt == qt - 8);
    if (need_mask) {
      const int dbase = (k0 + lc) - (q0 + 16 * w + 4 * quad);
      #pragma unroll
      for (int g = 0; g < 4; ++g)
        #pragma unroll
        for (int r = 0; r < 4; ++r) {
          int dji = dbase + 16 * g - r;
          float s = accs[g][r];
          s = (dji <= 0 && dji >= -(WIN - 1)) ? s : -1e30f;
          p[g][r] = s;
          tm[r] = fmaxf(tm[r], s);
        }
    } else {
      #pragma unroll
      for (int g = 0; g < 4; ++g)
        #pragma unroll
        for (int r = 0; r < 4; ++r) {
          p[g][r] = accs[g][r];
          tm[r] = fmaxf(tm[r], accs[g][r]);
        }
    }
    #pragma unroll
    for (int off = 1; off < 16; off <<= 1)
      #pragma unroll
      for (int r = 0; r < 4; ++r)
        tm[r] = fmaxf(tm[r], __shfl_xor(tm[r], off, 64));

    float alpha[4], tsum[4];
    #pragma unroll
    for (int r = 0; r < 4; ++r) {
      float mn = fmaxf(m_r[r], tm[r]);
      alpha[r] = __expf(m_r[r] - mn);
      m_r[r] = mn;
      tsum[r] = 0.0f;
    }
    #pragma unroll
    for (int g = 0; g < 4; ++g)
      #pragma unroll
      for (int r = 0; r < 4; ++r) {
        float e = __expf(p[g][r] - m_r[r]);
        p[g][r] = e;
        tsum[r] += e;
      }
    #pragma unroll
    for (int off = 1; off < 16; off <<= 1)
      #pragma unroll
      for (int r = 0; r < 4; ++r)
        tsum[r] += __shfl_xor(tsum[r], off, 64);
    #pragma unroll
    for (int r = 0; r < 4; ++r) l_r[r] = l_r[r] * alpha[r] + tsum[r];
    #pragma unroll
    for (int g = 0; g < 4; ++g)
      #pragma unroll
      for (int r = 0; r < 4; ++r) acc_o[g][r] *= alpha[r];

    // ---- P: C-layout -> A-layout via per-wave swizzled LDS ----
    #pragma unroll
    for (int g = 0; g < 4; ++g)
      #pragma unroll
      for (int r = 0; r < 4; ++r) {
        int row = 4 * quad + r;
        int blk = 2 * g + (lc >> 3);
        int addr = row * 128 + ((blk ^ (row & 7)) << 4) + lc7 * 2;
        *(ushort_t*)((char*)&Ps[w][0] + addr) = f2bf(p[g][r]);
      }
    __asm__ __volatile__("s_waitcnt lgkmcnt(0)" ::: "memory");

    bf16x8 pa0 = *(const bf16x8*)((const char*)&Ps[w][0] + kbase0);
    bf16x8 pa1 = *(const bf16x8*)((const char*)&Ps[w][0] + kbase1);

    // ---- O += P V ----
    #pragma unroll
    for (int gn = 0; gn < 4; ++gn) {
      bf16x8 vb0 = *(const bf16x8*)((const char*)&Vt[buf][0] + kbase0 + gn * 2048);
      bf16x8 vb1 = *(const bf16x8*)((const char*)&Vt[buf][0] + kbase1 + gn * 2048);
      f32x4 c = acc_o[gn];
      c = __builtin_amdgcn_mfma_f32_16x16x32_bf16(pa0, vb0, c, 0, 0, 0);
      c = __builtin_amdgcn_mfma_f32_16x16x32_bf16(pa1, vb1, c, 0, 0, 0);
      acc_o[gn] = c;
    }

    buf ^= 1;
  }

  // ---- epilogue ----
  float rcp[4];
  #pragma unroll
  for (int r = 0; r < 4; ++r) rcp[r] = 1.0f / l_r[r];
  #pragma unroll
  for (int gn = 0; gn < 4; ++gn)
    #pragma unroll
    for (int r = 0; r < 4; ++r) {
      int row = q0 + 16 * w + 4 * quad + r;
      Og[base + (size_t)row * DH + 16 * gn + lc] = acc_o[gn][r] * rcp[r];
    }
}

// ---------------------------------------------------------------------------
// Fallback (R1 kernel) if workspace is too small for the bf16 tile cache.
// ---------------------------------------------------------------------------
#define LDP 72
__global__ __launch_bounds__(256) void swa_attn_fallback(
    const float* __restrict__ Qg, const float* __restrict__ Kg,
    const float* __restrict__ Vg, float* __restrict__ Og)
{
  const int qt = blockIdx.x;
  const int bh = blockIdx.y;
  const int q0 = qt * QT;
  const size_t base = (size_t)bh * SEQ * DH;
  const int t = threadIdx.x, w = t >> 6, l = t & 63, quad = l >> 4, lc = l & 15;

  __shared__ unsigned short Qs[QT][LDP];
  __shared__ unsigned short KsF[QT][LDP];
  __shared__ unsigned short VtF[DH][LDP];
  __shared__ unsigned short PsF[4][16][LDP];

  {
    const float* src = Qg + base + (size_t)q0 * DH;
    #pragma unroll
    for (int i = 0; i < 4; ++i) {
      int e = t + 256 * i, row = e >> 4, d4 = (e & 15) * 4;
      float4 v = *(const float4*)(src + row * DH + d4);
      ushort4 o; o.x=f2bf(v.x*0.125f); o.y=f2bf(v.y*0.125f); o.z=f2bf(v.z*0.125f); o.w=f2bf(v.w*0.125f);
      *(ushort4*)&Qs[row][d4] = o;
    }
  }
  __syncthreads();
  bf16x8 aq0 = *(const bf16x8*)&Qs[16*w+lc][0 + 8*quad];
  bf16x8 aq1 = *(const bf16x8*)&Qs[16*w+lc][32 + 8*quad];

  float m_r[4], l_r[4]; f32x4 acc_o[4];
  #pragma unroll
  for (int r = 0; r < 4; ++r) { m_r[r] = -1e30f; l_r[r] = 0.0f; }
  #pragma unroll
  for (int g = 0; g < 4; ++g) { acc_o[g][0]=0.f; acc_o[g][1]=0.f; acc_o[g][2]=0.f; acc_o[g][3]=0.f; }
  const int kt_lo = (qt - 8 > 0) ? (qt - 8) : 0;

  for (int kt = qt; kt >= kt_lo; --kt) {
    const int k0 = kt * QT;
    __syncthreads();
    {
      const float* srcK = Kg + base + (size_t)k0 * DH;
      const float* srcV = Vg + base + (size_t)k0 * DH;
      #pragma unroll
      for (int i = 0; i < 4; ++i) {
        int e = t + 256 * i, row = e >> 4, d4 = (e & 15) * 4;
        float4 kv = *(const float4*)(srcK + row * DH + d4);
        ushort4 ko; ko.x=f2bf(kv.x); ko.y=f2bf(kv.y); ko.z=f2bf(kv.z); ko.w=f2bf(kv.w);
        *(ushort4*)&KsF[row][d4] = ko;
        float4 vv = *(const float4*)(srcV + row * DH + d4);
        VtF[d4+0][row]=f2bf(vv.x); VtF[d4+1][row]=f2bf(vv.y);
        VtF[d4+2][row]=f2bf(vv.z); VtF[d4+3][row]=f2bf(vv.w);
      }
    }
    __syncthreads();

    f32x4 accs[4];
    #pragma unroll
    for (int g = 0; g < 4; ++g) {
      bf16x8 b0 = *(const bf16x8*)&KsF[16*g+lc][0 + 8*quad];
      bf16x8 b1 = *(const bf16x8*)&KsF[16*g+lc][32 + 8*quad];
      f32x4 c; c[0]=0.f; c[1]=0.f; c[2]=0.f; c[3]=0.f;
      c = __builtin_amdgcn_mfma_f32_16x16x32_bf16(aq0, b0, c, 0, 0, 0);
      c = __builtin_amdgcn_mfma_f32_16x16x32_bf16(aq1, b1, c, 0, 0, 0);
      accs[g] = c;
    }
    const int dbase = (k0 + lc) - (q0 + 16*w + 4*quad);
    float p[4][4], tm[4];
    #pragma unroll
    for (int r = 0; r < 4; ++r) tm[r] = -1e30f;
    #pragma unroll
    for (int g = 0; g < 4; ++g)
      #pragma unroll
      for (int r = 0; r < 4; ++r) {
        int dji = dbase + 16*g - r;
        float s = accs[g][r];
        s = (dji <= 0 && dji >= -(WIN-1)) ? s : -1e30f;
        p[g][r] = s; tm[r] = fmaxf(tm[r], s);
      }
    #pragma unroll
    for (int off = 1; off < 16; off <<= 1)
      #pragma unroll
      for (int r = 0; r < 4; ++r) tm[r] = fmaxf(tm[r], __shfl_xor(tm[r], off, 64));
    float alpha[4], tsum[4];
    #pragma unroll
    for (int r = 0; r < 4; ++r) {
      float mn = fmaxf(m_r[r], tm[r]);
      alpha[r] = __expf(m_r[r] - mn); m_r[r] = mn; tsum[r] = 0.0f;
    }
    #pragma unroll
    for (int g = 0; g < 4; ++g)
      #pragma unroll
      for (int r = 0; r < 4; ++r) { float e = __expf(p[g][r]-m_r[r]); p[g][r]=e; tsum[r]+=e; }
    #pragma unroll
    for (int off = 1; off < 16; off <<= 1)
      #pragma unroll
      for (int r = 0; r < 4; ++r) tsum[r] += __shfl_xor(tsum[r], off, 64);
    #pragma unroll
    for (int r = 0; r < 4; ++r) l_r[r] = l_r[r]*alpha[r] + tsum[r];
    #pragma unroll
    for (int g = 0; g < 4; ++g)
      #pragma unroll
      for (int r = 0; r < 4; ++r) acc_o[g][r] *= alpha[r];
    #pragma unroll
    for (int g = 0; g < 4; ++g)
      #pragma unroll
      for (int r = 0; r < 4; ++r)
        PsF[w][4*quad+r][16*g+lc] = f2bf(p[g][r]);
    __asm__ __volatile__("s_waitcnt lgkmcnt(0)" ::: "memory");
    bf16x8 pa0 = *(const bf16x8*)&PsF[w][lc][0 + 8*quad];
    bf16x8 pa1 = *(const bf16x8*)&PsF[w][lc][32 + 8*quad];
    #pragma unroll
    for (int gn = 0; gn < 4; ++gn) {
      bf16x8 vb0 = *(const bf16x8*)&VtF[16*gn+lc][0 + 8*quad];
      bf16x8 vb1 = *(const bf16x8*)&VtF[16*gn+lc][32 + 8*quad];
      f32x4 c = acc_o[gn];
      c = __builtin_amdgcn_mfma_f32_16x16x32_bf16(pa0, vb0, c, 0, 0, 0);
      c = __builtin_amdgcn_mfma_f32_16x16x32_bf16(pa1, vb1, c, 0, 0, 0);
      acc_o[gn] = c;
    }
  }
  #pragma unroll
  for (int gn = 0; gn < 4; ++gn)
    #pragma unroll
    for (int r = 0; r < 4; ++r) {
      int row = q0 + 16*w + 4*quad + r;
      Og[base + (size_t)row * DH + 16*gn + lc] = acc_o[gn][r] / l_r[r];
    }
}

extern "C" void kernel_launch(void* const* d_in, const int* in_sizes, int n_in,
                              void* d_out, int out_size, void* d_ws, size_t ws_size,
                              hipStream_t stream) {
  const float* Q = (const float*)d_in[0];
  const float* K = (const float*)d_in[1];
  const float* V = (const float*)d_in[2];
  float* O = (float*)d_out;

  const size_t kbytes = (size_t)NBATCH * NHEAD * 64 * 8192;  // 8 MB
  if (ws_size >= 2 * kbytes) {
    ushort_t* Kw = (ushort_t*)d_ws;
    ushort_t* Vw = (ushort_t*)((char*)d_ws + kbytes);
    dim3 grid(SEQ / QT, NBATCH * NHEAD);
    prep_kernel<<<grid, dim3(256), 0, stream>>>(K, V, Kw, Vw);
    swa_attn_kernel<<<grid, dim3(256), 0, stream>>>(Q, Kw, Vw, O);
  } else {
    dim3 grid(SEQ / QT, NBATCH * NHEAD);
    swa_attn_fallback<<<grid, dim3(256), 0, stream>>>(Q, K, V, O);
  }
}